// Round 2
// baseline (401.860 us; speedup 1.0000x reference)
//
#include <hip/hip_runtime.h>

typedef __attribute__((ext_vector_type(8))) short bf16x8;
typedef __attribute__((ext_vector_type(4))) float f32x4;

constexpr int Bb = 32, Cc = 256, Nn = 1024;
constexpr float EPSf = 1e-5f;
constexpr float SCALE = 0.0625f; // 256^-0.5

__device__ __forceinline__ unsigned short f2bf(float f) {
  union { float f; unsigned u; } v; v.f = f;
  unsigned r = v.u + 0x7fffu + ((v.u >> 16) & 1u);
  return (unsigned short)(r >> 16);
}

__device__ __forceinline__ bf16x8 ldb8(const unsigned short* p) {
  return *reinterpret_cast<const bf16x8*>(p);
}

// ---------------- weight fp32 -> bf16 ----------------
__global__ void cvt_w_kernel(const float* __restrict__ wq, const float* __restrict__ wk,
                             const float* __restrict__ wv, const float* __restrict__ wo,
                             unsigned short* __restrict__ o) {
  int i = blockIdx.x * 256 + threadIdx.x;  // grid 256 x 256 = 65536
  o[i]          = f2bf(wq[i]);
  o[65536 + i]  = f2bf(wk[i]);
  o[131072 + i] = f2bf(wv[i]);
  o[196608 + i] = f2bf(wo[i]);
}

// ---------------- groupnorm stats: one block per (b,group) ----------------
__global__ void gn_stats_kernel(const float* __restrict__ x, float2* __restrict__ stats) {
  const float4* p = reinterpret_cast<const float4*>(x + (size_t)blockIdx.x * 8192);
  float s = 0.f, ss = 0.f;
  for (int i = threadIdx.x; i < 2048; i += 256) {
    float4 v = p[i];
    s  += v.x + v.y + v.z + v.w;
    ss += v.x * v.x + v.y * v.y + v.z * v.z + v.w * v.w;
  }
  for (int o = 1; o < 64; o <<= 1) { s += __shfl_xor(s, o, 64); ss += __shfl_xor(ss, o, 64); }
  __shared__ float rs[4], rss[4];
  int wid = threadIdx.x >> 6;
  if ((threadIdx.x & 63) == 0) { rs[wid] = s; rss[wid] = ss; }
  __syncthreads();
  if (threadIdx.x == 0) {
    float S = rs[0] + rs[1] + rs[2] + rs[3];
    float SS = rss[0] + rss[1] + rss[2] + rss[3];
    float mean = S * (1.f / 8192.f);
    float var  = SS * (1.f / 8192.f) - mean * mean;
    stats[blockIdx.x] = make_float2(mean, rsqrtf(var + EPSf));
  }
}

// ---------------- groupnorm apply: x[B,C,N] -> hT[B,N,C] bf16 ----------------
__global__ void gn_apply_kernel(const float* __restrict__ x, const float2* __restrict__ stats,
                                const float* __restrict__ gw, const float* __restrict__ gb,
                                unsigned short* __restrict__ hT) {
  int b = blockIdx.y;
  int n = blockIdx.x * 64 + (threadIdx.x & 63);
  int c0 = (threadIdx.x >> 6) * 64;
  const float* xb = x + (size_t)b * Cc * Nn;
  unsigned short* orow = hT + ((size_t)b * Nn + n) * Cc;
  for (int cc = 0; cc < 64; cc += 8) {
    union { unsigned short u[8]; uint4 v; } pk;
#pragma unroll
    for (int k = 0; k < 8; ++k) {
      int c = c0 + cc + k;
      float2 st = stats[b * 32 + (c >> 3)];
      float val = (xb[(size_t)c * Nn + n] - st.x) * st.y * gw[c] + gb[c];
      pk.u[k] = f2bf(val);
    }
    *reinterpret_cast<uint4*>(orow + c0 + cc) = pk.v;
  }
}

// ---------------- generic bf16 GEMM: D[row,col] = sum_k A[row,k]*Bt[col,k] + bias ----------------
__global__ void __launch_bounds__(256) gemm_bt_kernel(
    const unsigned short* __restrict__ A, size_t sA,
    const unsigned short* __restrict__ Bt, size_t sB,
    unsigned short* __restrict__ O, size_t sO,
    const float* __restrict__ bias, int biasRow,
    int lda, int ldb, int ldo) {
  int bz = blockIdx.z;
  A += (size_t)bz * sA; Bt += (size_t)bz * sB; O += (size_t)bz * sO;
  int lane = threadIdx.x & 63, wid = threadIdx.x >> 6;
  int lr = lane & 15, lg = lane >> 4;
  int row0 = blockIdx.x * 128 + (wid >> 1) * 64;
  int col0 = blockIdx.y * 128 + (wid & 1) * 64;
  f32x4 acc[4][4] = {};
  for (int k0 = 0; k0 < 256; k0 += 32) {
    bf16x8 a[4], bb[4];
#pragma unroll
    for (int i = 0; i < 4; ++i) a[i] = ldb8(A + (size_t)(row0 + 16 * i + lr) * lda + k0 + 8 * lg);
#pragma unroll
    for (int j = 0; j < 4; ++j) bb[j] = ldb8(Bt + (size_t)(col0 + 16 * j + lr) * ldb + k0 + 8 * lg);
#pragma unroll
    for (int i = 0; i < 4; ++i)
#pragma unroll
      for (int j = 0; j < 4; ++j)
        acc[i][j] = __builtin_amdgcn_mfma_f32_16x16x32_bf16(a[i], bb[j], acc[i][j], 0, 0, 0);
  }
#pragma unroll
  for (int i = 0; i < 4; ++i)
#pragma unroll
    for (int j = 0; j < 4; ++j)
#pragma unroll
      for (int r = 0; r < 4; ++r) {
        int row = row0 + 16 * i + 4 * lg + r;
        int col = col0 + 16 * j + lr;
        float v = acc[i][j][r] + (biasRow ? bias[row] : bias[col]);
        O[(size_t)row * ldo + col] = f2bf(v);
      }
}

// ---------------- fused Q-proj + flash attention, in-place output over hT ----------------
// hT: [BG,N,C] bf16 (groupnormed h, rows overwritten with attention output)
__global__ void __launch_bounds__(256) attn_kernel(
    const unsigned short* __restrict__ wqb, const float* __restrict__ bq,
    unsigned short* __restrict__ hT,
    const unsigned short* __restrict__ KT, const unsigned short* __restrict__ VT) {
  int b = blockIdx.y;
  int lane = threadIdx.x & 63, wid = threadIdx.x >> 6;
  int lr = lane & 15, lg = lane >> 4;
  int n0 = blockIdx.x * 64 + wid * 16;
  unsigned short* hb = hT + (size_t)b * Nn * Cc;
  unsigned short* hrow = hb + (size_t)(n0 + lr) * Cc;  // this wave's 16 rows (by lr)
  const unsigned short* KTb = KT + (size_t)b * Nn * Cc;
  const unsigned short* VTb = VT + (size_t)b * Cc * Nn;

  __shared__ unsigned short qlds[4][16][256];  // 32KB, per-wave private slice
  char* qbase = (char*)&qlds[wid][0][0];

  // ---- Q on the fly: Q[n0+lr][ch] = (sum_c h[n0+lr][c]*wq[ch][c] + bq[ch]) * SCALE
  {
    bf16x8 hfrag[8];
#pragma unroll
    for (int kk = 0; kk < 8; ++kk) hfrag[kk] = ldb8(hrow + 32 * kk + 8 * lg);
#pragma unroll
    for (int t = 0; t < 16; ++t) {
      f32x4 aq = {0.f, 0.f, 0.f, 0.f};
#pragma unroll
      for (int kk = 0; kk < 8; ++kk) {
        bf16x8 wf = ldb8(wqb + (size_t)(16 * t + lr) * Cc + 32 * kk + 8 * lg);
        aq = __builtin_amdgcn_mfma_f32_16x16x32_bf16(wf, hfrag[kk], aq, 0, 0, 0);
      }
      union { unsigned short u[4]; uint2 v; } pk;
#pragma unroll
      for (int r = 0; r < 4; ++r) pk.u[r] = f2bf((aq[r] + bq[16 * t + 4 * lg + r]) * SCALE);
      int woff = (lr * 512 + (16 * t + 4 * lg) * 2) ^ ((lr & 7) << 4);
      *reinterpret_cast<uint2*>(qbase + woff) = pk.v;
    }
  }
  bf16x8 q[8];
#pragma unroll
  for (int kk = 0; kk < 8; ++kk) {
    int roff = (lr * 512 + (32 * kk + 8 * lg) * 2) ^ ((lr & 7) << 4);
    q[kk] = *reinterpret_cast<bf16x8*>(qbase + roff);
  }

  f32x4 acc[16] = {};
  float mrun = -1e30f, lrun = 0.f;
  for (int m0 = 0; m0 < Nn; m0 += 32) {
    f32x4 st0 = {0.f, 0.f, 0.f, 0.f}, st1 = {0.f, 0.f, 0.f, 0.f};
#pragma unroll
    for (int kk = 0; kk < 8; ++kk) {
      bf16x8 k0 = ldb8(KTb + (size_t)(m0 + lr) * Cc + 32 * kk + 8 * lg);
      bf16x8 k1 = ldb8(KTb + (size_t)(m0 + 16 + lr) * Cc + 32 * kk + 8 * lg);
      st0 = __builtin_amdgcn_mfma_f32_16x16x32_bf16(k0, q[kk], st0, 0, 0, 0);
      st1 = __builtin_amdgcn_mfma_f32_16x16x32_bf16(k1, q[kk], st1, 0, 0, 0);
    }
    // ST[m][n]: lane holds m = m0 + 4*lg + r (+16 for st1), n = n0 + lr (scale folded into Q)
    float s0[4], s1[4];
    float tm = -1e30f;
#pragma unroll
    for (int r = 0; r < 4; ++r) {
      s0[r] = st0[r]; s1[r] = st1[r];
      tm = fmaxf(tm, fmaxf(s0[r], s1[r]));
    }
    tm = fmaxf(tm, __shfl_xor(tm, 16, 64));
    tm = fmaxf(tm, __shfl_xor(tm, 32, 64));
    // defer-max: only rescale when the running max grows by > 8
    if (!__all(tm - mrun <= 8.f)) {
      float mnew = fmaxf(mrun, tm);
      float alpha = __expf(mrun - mnew);
#pragma unroll
      for (int t = 0; t < 16; ++t) {
        acc[t][0] *= alpha; acc[t][1] *= alpha; acc[t][2] *= alpha; acc[t][3] *= alpha;
      }
      lrun *= alpha;
      mrun = mnew;
    }
    float p0[4], p1[4], ps = 0.f;
#pragma unroll
    for (int r = 0; r < 4; ++r) {
      p0[r] = __expf(s0[r] - mrun); p1[r] = __expf(s1[r] - mrun);
      ps += p0[r] + p1[r];
    }
    ps += __shfl_xor(ps, 16, 64);
    ps += __shfl_xor(ps, 32, 64);
    lrun += ps;
    // Build P as MFMA B-operand: slot j needs P[m_local = 8*lg + j] of column lr.
    bf16x8 pb;
#pragma unroll
    for (int j = 0; j < 8; ++j) {
      int sl = lr + 16 * ((j >> 2) + 2 * (lg & 1));
      float v0 = __shfl(p0[j & 3], sl, 64);
      float v1 = __shfl(p1[j & 3], sl, 64);
      pb[j] = (short)f2bf((lg >> 1) ? v1 : v0);
    }
#pragma unroll
    for (int t = 0; t < 16; ++t) {
      bf16x8 va = ldb8(VTb + (size_t)(16 * t + lr) * Nn + m0 + 8 * lg);
      acc[t] = __builtin_amdgcn_mfma_f32_16x16x32_bf16(va, pb, acc[t], 0, 0, 0);
    }
  }
  float inv = 1.f / lrun;
  unsigned short* ho = hrow;  // in-place: each block touches only its own rows
#pragma unroll
  for (int t = 0; t < 16; ++t) {
    union { unsigned short u[4]; uint2 v; } pk;
#pragma unroll
    for (int r = 0; r < 4; ++r) pk.u[r] = f2bf(acc[t][r] * inv);
    *reinterpret_cast<uint2*>(ho + 16 * t + 4 * lg) = pk.v;
  }
}

// ---------------- output projection + bias + residual, fp32 out ----------------
__global__ void __launch_bounds__(256) proj_res_kernel(
    const unsigned short* __restrict__ Wo, const unsigned short* __restrict__ HO,
    const float* __restrict__ bo, const float* __restrict__ x, float* __restrict__ out) {
  int b = blockIdx.z;
  int lane = threadIdx.x & 63, wid = threadIdx.x >> 6;
  int lr = lane & 15, lg = lane >> 4;
  int row0 = blockIdx.x * 128 + (wid >> 1) * 64;  // o
  int col0 = blockIdx.y * 128 + (wid & 1) * 64;   // n
  const unsigned short* hb = HO + (size_t)b * Nn * Cc;
  f32x4 acc[4][4] = {};
  for (int k0 = 0; k0 < 256; k0 += 32) {
    bf16x8 a[4], bb[4];
#pragma unroll
    for (int i = 0; i < 4; ++i) a[i] = ldb8(Wo + (size_t)(row0 + 16 * i + lr) * Cc + k0 + 8 * lg);
#pragma unroll
    for (int j = 0; j < 4; ++j) bb[j] = ldb8(hb + (size_t)(col0 + 16 * j + lr) * Cc + k0 + 8 * lg);
#pragma unroll
    for (int i = 0; i < 4; ++i)
#pragma unroll
      for (int j = 0; j < 4; ++j)
        acc[i][j] = __builtin_amdgcn_mfma_f32_16x16x32_bf16(a[i], bb[j], acc[i][j], 0, 0, 0);
  }
  const float* xb = x + (size_t)b * Cc * Nn;
  float* ob = out + (size_t)b * Cc * Nn;
#pragma unroll
  for (int i = 0; i < 4; ++i)
#pragma unroll
    for (int j = 0; j < 4; ++j)
#pragma unroll
      for (int r = 0; r < 4; ++r) {
        int o = row0 + 16 * i + 4 * lg + r;
        int n = col0 + 16 * j + lr;
        size_t idx = (size_t)o * Nn + n;
        ob[idx] = xb[idx] + bo[o] + acc[i][j][r];
      }
}

extern "C" void kernel_launch(void* const* d_in, const int* in_sizes, int n_in,
                              void* d_out, int out_size, void* d_ws, size_t ws_size,
                              hipStream_t stream) {
  const float* x  = (const float*)d_in[0];
  const float* gw = (const float*)d_in[1];
  const float* gb = (const float*)d_in[2];
  const float* wq = (const float*)d_in[3];
  const float* bq = (const float*)d_in[4];
  const float* wk = (const float*)d_in[5];
  const float* bk = (const float*)d_in[6];
  const float* wv = (const float*)d_in[7];
  const float* bv = (const float*)d_in[8];
  const float* wo = (const float*)d_in[9];
  const float* bo = (const float*)d_in[10];
  float* out = (float*)d_out;
  char* ws = (char*)d_ws;

  // workspace layout — NEVER exceed ws_size:
  //   [0, 512KB)        wbf: 4 weight matrices in bf16
  //   [512KB, 520KB)    stats
  //   [1MB, 17MB)       hT [B,N,C] bf16 (becomes attention output in-place)
  //   [17MB, ...)       K^T/V^T staging for BG batches (BG*1MB), BG adapted to ws_size
  unsigned short* wbf  = (unsigned short*)ws;
  float2*        stats = (float2*)(ws + 524288);
  unsigned short* hT   = (unsigned short*)(ws + (1 << 20));
  const size_t KV_OFF = (size_t)17 << 20;
  const size_t perBatchKV = (size_t)Nn * Cc * 2 * 2;  // 1MB (KT + VT)
  size_t avail = ws_size > KV_OFF ? ws_size - KV_OFF : 0;
  int BG = 32;
  while (BG > 1 && (size_t)BG * perBatchKV > avail) BG >>= 1;

  cvt_w_kernel<<<dim3(256), dim3(256), 0, stream>>>(wq, wk, wv, wo, wbf);
  gn_stats_kernel<<<dim3(Bb * 32), dim3(256), 0, stream>>>(x, stats);
  gn_apply_kernel<<<dim3(Nn / 64, Bb), dim3(256), 0, stream>>>(x, stats, gw, gb, hT);

  unsigned short* KTg = (unsigned short*)(ws + KV_OFF);
  unsigned short* VTg = KTg + (size_t)BG * Nn * Cc;

  for (int g = 0; g < Bb; g += BG) {
    unsigned short* hTg = hT + (size_t)g * Nn * Cc;
    // KT[n][o] = sum_c hT[n][c] wk[o][c] + bk[o]   (stored [N,C] per batch)
    gemm_bt_kernel<<<dim3(8, 2, BG), dim3(256), 0, stream>>>(
        hTg, (size_t)Nn * Cc, wbf + 65536, 0, KTg, (size_t)Nn * Cc, bk, 0, Cc, Cc, Cc);
    // VT[o][n] = sum_c wv[o][c] hT[n][c] + bv[o]   (stored [C,N] per batch)
    gemm_bt_kernel<<<dim3(2, 8, BG), dim3(256), 0, stream>>>(
        wbf + 131072, 0, hTg, (size_t)Nn * Cc, VTg, (size_t)Cc * Nn, bv, 1, Cc, Cc, Nn);
    // fused Q-proj + attention, output in-place over hTg rows
    attn_kernel<<<dim3(Nn / 64, BG), dim3(256), 0, stream>>>(wbf, bq, hTg, KTg, VTg);
  }

  proj_res_kernel<<<dim3(2, 8, Bb), dim3(256), 0, stream>>>(wbf + 196608, hT, bo, x, out);
}

// Round 3
// 229.675 us; speedup vs baseline: 1.7497x; 1.7497x over previous
//
#include <hip/hip_runtime.h>

typedef __attribute__((ext_vector_type(8))) short bf16x8;
typedef __attribute__((ext_vector_type(4))) float f32x4;

constexpr int Bb = 32, Cc = 256, Nn = 1024;
constexpr float EPSf = 1e-5f;
constexpr float SCALE = 0.0625f; // 256^-0.5

__device__ __forceinline__ unsigned short f2bf(float f) {
  union { float f; unsigned u; } v; v.f = f;
  unsigned r = v.u + 0x7fffu + ((v.u >> 16) & 1u);
  return (unsigned short)(r >> 16);
}

__device__ __forceinline__ bf16x8 ldb8(const unsigned short* p) {
  return *reinterpret_cast<const bf16x8*>(p);
}

__device__ __forceinline__ void gload16(const void* g, void* l) {
  __builtin_amdgcn_global_load_lds((const __attribute__((address_space(1))) void*)g,
                                   (__attribute__((address_space(3))) void*)l, 16, 0, 0);
}

// ---------------- weight fp32 -> bf16 ----------------
__global__ void cvt_w_kernel(const float* __restrict__ wq, const float* __restrict__ wk,
                             const float* __restrict__ wv, const float* __restrict__ wo,
                             unsigned short* __restrict__ o) {
  int i = blockIdx.x * 256 + threadIdx.x;  // grid 256 x 256 = 65536
  o[i]          = f2bf(wq[i]);
  o[65536 + i]  = f2bf(wk[i]);
  o[131072 + i] = f2bf(wv[i]);
  o[196608 + i] = f2bf(wo[i]);
}

// ---------------- fused groupnorm: stats + apply in one pass ----------------
// block = one (b, group): 8 channels x 1024 spatial, staged in 32KB LDS
__global__ void __launch_bounds__(256) gn_fused_kernel(
    const float* __restrict__ x, const float* __restrict__ gw, const float* __restrict__ gb,
    unsigned short* __restrict__ hT) {
  int b = blockIdx.x >> 5, g = blockIdx.x & 31;
  const float4* xg = (const float4*)(x + ((size_t)b * 32 + g) * 8192);
  __shared__ float xs[8192];
  __shared__ float red[8];
  float s = 0.f, ss = 0.f;
  for (int i = threadIdx.x; i < 2048; i += 256) {
    float4 v = xg[i];
    ((float4*)xs)[i] = v;
    s += v.x + v.y + v.z + v.w;
    ss += v.x * v.x + v.y * v.y + v.z * v.z + v.w * v.w;
  }
  for (int o = 1; o < 64; o <<= 1) { s += __shfl_xor(s, o, 64); ss += __shfl_xor(ss, o, 64); }
  int wid = threadIdx.x >> 6;
  if ((threadIdx.x & 63) == 0) { red[wid] = s; red[4 + wid] = ss; }
  __syncthreads();
  float S  = red[0] + red[1] + red[2] + red[3];
  float SS = red[4] + red[5] + red[6] + red[7];
  float mean = S * (1.f / 8192.f);
  float rstd = rsqrtf(SS * (1.f / 8192.f) - mean * mean + EPSf);
  float w8[8], b8[8];
#pragma unroll
  for (int c = 0; c < 8; ++c) {
    w8[c] = gw[g * 8 + c] * rstd;
    b8[c] = gb[g * 8 + c] - mean * w8[c];
  }
  unsigned short* ob = hT + (size_t)b * Nn * Cc + g * 8;
#pragma unroll
  for (int k = 0; k < 4; ++k) {
    int n = threadIdx.x + 256 * k;
    union { unsigned short u[8]; uint4 v; } pk;
#pragma unroll
    for (int c = 0; c < 8; ++c) pk.u[c] = f2bf(xs[c * 1024 + n] * w8[c] + b8[c]);
    *reinterpret_cast<uint4*>(ob + (size_t)n * Cc) = pk.v;
  }
}

// ---------------- generic bf16 GEMM: D[row,col] = sum_k A[row,k]*Bt[col,k] + bias ----------------
__global__ void __launch_bounds__(256) gemm_bt_kernel(
    const unsigned short* __restrict__ A, size_t sA,
    const unsigned short* __restrict__ Bt, size_t sB,
    unsigned short* __restrict__ O, size_t sO,
    const float* __restrict__ bias, int biasRow,
    int lda, int ldb, int ldo) {
  int bz = blockIdx.z;
  A += (size_t)bz * sA; Bt += (size_t)bz * sB; O += (size_t)bz * sO;
  int lane = threadIdx.x & 63, wid = threadIdx.x >> 6;
  int lr = lane & 15, lg = lane >> 4;
  int row0 = blockIdx.x * 128 + (wid >> 1) * 64;
  int col0 = blockIdx.y * 128 + (wid & 1) * 64;
  f32x4 acc[4][4] = {};
  for (int k0 = 0; k0 < 256; k0 += 32) {
    bf16x8 a[4], bb[4];
#pragma unroll
    for (int i = 0; i < 4; ++i) a[i] = ldb8(A + (size_t)(row0 + 16 * i + lr) * lda + k0 + 8 * lg);
#pragma unroll
    for (int j = 0; j < 4; ++j) bb[j] = ldb8(Bt + (size_t)(col0 + 16 * j + lr) * ldb + k0 + 8 * lg);
#pragma unroll
    for (int i = 0; i < 4; ++i)
#pragma unroll
      for (int j = 0; j < 4; ++j)
        acc[i][j] = __builtin_amdgcn_mfma_f32_16x16x32_bf16(a[i], bb[j], acc[i][j], 0, 0, 0);
  }
#pragma unroll
  for (int i = 0; i < 4; ++i)
#pragma unroll
    for (int j = 0; j < 4; ++j)
#pragma unroll
      for (int r = 0; r < 4; ++r) {
        int row = row0 + 16 * i + 4 * lg + r;
        int col = col0 + 16 * j + lr;
        float v = acc[i][j][r] + (biasRow ? bias[row] : bias[col]);
        O[(size_t)row * ldo + col] = f2bf(v);
      }
}

// ---------------- fused Q-proj + flash attention with LDS K/V double-buffer ----------------
// hT: [BG,N,C] bf16 (groupnormed h; rows overwritten in-place with attention output)
__global__ void __launch_bounds__(256) attn_kernel(
    const unsigned short* __restrict__ wqb, const float* __restrict__ bq,
    unsigned short* __restrict__ hT,
    const unsigned short* __restrict__ KT, const unsigned short* __restrict__ VT) {
  int b = blockIdx.y;
  int tid = threadIdx.x;
  int lane = tid & 63, wid = tid >> 6;
  int lr = lane & 15, lg = lane >> 4;
  int n0 = blockIdx.x * 64 + wid * 16;
  unsigned short* hrow = hT + ((size_t)b * Nn + n0 + lr) * Cc;  // wave's 16 rows (by lr)
  const char* KTb = (const char*)(KT + (size_t)b * Nn * Cc);
  const char* VTb = (const char*)(VT + (size_t)b * Cc * Nn);

  // LDS: [0,16K) K buf0 | [16K,32K) V buf0 | [32K,48K) K buf1 | [48K,64K) V buf1
  // Q staging transiently aliases [32K,64K) before the m-loop.
  __shared__ alignas(16) char lds[65536];

  // stage tile (32 KV rows): K tile 16KB rows of 512B, V tile 16KB rows of 64B.
  // global_load_lds writes linearly (base+lane*16); bank-conflict-free reads need a
  // row-XOR swizzle, so the *source* global address is inverse-swizzled (involution).
  auto stage = [&](int t, int buf) {
    char* kdst = lds + buf * 32768;
    char* vdst = kdst + 16384;
    const char* kg = KTb + (size_t)t * 32 * 512;  // 32 rows of K^T [N,C]
    const char* vg = VTb + (size_t)t * 64;        // 32 cols (2B each) of V^T [C,N]
#pragma unroll
    for (int r = 0; r < 4; ++r) {
      int Lb = r * 4096 + wid * 1024;
      int L = Lb + lane * 16;
      int lk = L ^ (((L >> 9) & 7) << 4);                 // K: 512B rows, swz bits 4-6
      gload16(kg + lk, kdst + Lb);
      int off = (L ^ (((L >> 7) & 3) << 4)) & 63;         // V: 64B rows, swz bits 4-5
      gload16(vg + (size_t)(L >> 6) * 2048 + off, vdst + Lb);
    }
  };

  stage(0, 0);  // overlap tile-0 staging with Q projection (disjoint LDS regions)

  // ---- Q on the fly: Q[n0+lr][ch] = (sum_c h[c]*wq[ch][c] + bq[ch]) * SCALE
  char* qbase = lds + 32768 + wid * 8192;
  {
    bf16x8 hfrag[8];
#pragma unroll
    for (int kk = 0; kk < 8; ++kk) hfrag[kk] = ldb8(hrow + 32 * kk + 8 * lg);
#pragma unroll
    for (int t = 0; t < 16; ++t) {
      f32x4 aq = {0.f, 0.f, 0.f, 0.f};
#pragma unroll
      for (int kk = 0; kk < 8; ++kk) {
        bf16x8 wf = ldb8(wqb + (size_t)(16 * t + lr) * Cc + 32 * kk + 8 * lg);
        aq = __builtin_amdgcn_mfma_f32_16x16x32_bf16(wf, hfrag[kk], aq, 0, 0, 0);
      }
      union { unsigned short u[4]; uint2 v; } pk;
#pragma unroll
      for (int r = 0; r < 4; ++r) pk.u[r] = f2bf((aq[r] + bq[16 * t + 4 * lg + r]) * SCALE);
      int woff = (lr * 512 + (16 * t + 4 * lg) * 2) ^ ((lr & 7) << 4);
      *reinterpret_cast<uint2*>(qbase + woff) = pk.v;
    }
  }
  bf16x8 q[8];
#pragma unroll
  for (int kk = 0; kk < 8; ++kk) {
    int roff = (lr * 512 + (32 * kk + 8 * lg) * 2) ^ ((lr & 7) << 4);
    q[kk] = *reinterpret_cast<bf16x8*>(qbase + roff);
  }
  __syncthreads();  // tile0 staged (vmcnt drained) + all waves done with Q region

  f32x4 acc[16] = {};
  float mrun = -1e30f, lrun = 0.f;
  for (int t = 0; t < 32; ++t) {
    int cur = t & 1;
    if (t < 31) stage(t + 1, cur ^ 1);
    const char* kbuf = lds + cur * 32768;
    const char* vbuf = kbuf + 16384;
    // ---- QK^T from LDS (swizzled reads, conflict-free)
    f32x4 st0 = {0.f, 0.f, 0.f, 0.f}, st1 = {0.f, 0.f, 0.f, 0.f};
#pragma unroll
    for (int kk = 0; kk < 8; ++kk) {
      int c = kk * 64 + lg * 16;
      int sx = (lr & 7) << 4;
      bf16x8 k0 = *reinterpret_cast<const bf16x8*>(kbuf + ((lr * 512 + c) ^ sx));
      bf16x8 k1 = *reinterpret_cast<const bf16x8*>(kbuf + (((lr + 16) * 512 + c) ^ sx));
      st0 = __builtin_amdgcn_mfma_f32_16x16x32_bf16(k0, q[kk], st0, 0, 0, 0);
      st1 = __builtin_amdgcn_mfma_f32_16x16x32_bf16(k1, q[kk], st1, 0, 0, 0);
    }
    // lane holds S^T[m = 4lg+r (+16)][n = n0+lr]
    float s0[4], s1[4], tm = -1e30f;
#pragma unroll
    for (int r = 0; r < 4; ++r) {
      s0[r] = st0[r]; s1[r] = st1[r];
      tm = fmaxf(tm, fmaxf(s0[r], s1[r]));
    }
    tm = fmaxf(tm, __shfl_xor(tm, 16, 64));
    tm = fmaxf(tm, __shfl_xor(tm, 32, 64));
    if (!__all(tm - mrun <= 8.f)) {  // defer-max (T13)
      float mnew = fmaxf(mrun, tm);
      float alpha = __expf(mrun - mnew);
#pragma unroll
      for (int u = 0; u < 16; ++u) {
        acc[u][0] *= alpha; acc[u][1] *= alpha; acc[u][2] *= alpha; acc[u][3] *= alpha;
      }
      lrun *= alpha;
      mrun = mnew;
    }
    float p0[4], p1[4], ps = 0.f;
#pragma unroll
    for (int r = 0; r < 4; ++r) {
      p0[r] = __expf(s0[r] - mrun); p1[r] = __expf(s1[r] - mrun);
      ps += p0[r] + p1[r];
    }
    ps += __shfl_xor(ps, 16, 64);
    ps += __shfl_xor(ps, 32, 64);
    lrun += ps;
    // ---- P -> bf16 packed, then redistribute (4 cvt_pk + 8 shuffles, T12-lite)
    unsigned w00, w01, w10, w11;
    asm("v_cvt_pk_bf16_f32 %0, %1, %2" : "=v"(w00) : "v"(p0[0]), "v"(p0[1]));
    asm("v_cvt_pk_bf16_f32 %0, %1, %2" : "=v"(w01) : "v"(p0[2]), "v"(p0[3]));
    asm("v_cvt_pk_bf16_f32 %0, %1, %2" : "=v"(w10) : "v"(p1[0]), "v"(p1[1]));
    asm("v_cvt_pk_bf16_f32 %0, %1, %2" : "=v"(w11) : "v"(p1[2]), "v"(p1[3]));
    int sl0 = lr + 16 * (2 * (lg & 1));
    int sl1 = sl0 + 16;
    int hi = lg >> 1;
    union { unsigned w[4]; bf16x8 v; } pbu;
    {
      unsigned a = __shfl(w00, sl0, 64), c = __shfl(w10, sl0, 64);
      pbu.w[0] = hi ? c : a;
      unsigned a1 = __shfl(w01, sl0, 64), c1 = __shfl(w11, sl0, 64);
      pbu.w[1] = hi ? c1 : a1;
      unsigned a2 = __shfl(w00, sl1, 64), c2 = __shfl(w10, sl1, 64);
      pbu.w[2] = hi ? c2 : a2;
      unsigned a3 = __shfl(w01, sl1, 64), c3 = __shfl(w11, sl1, 64);
      pbu.w[3] = hi ? c3 : a3;
    }
    // ---- PV from LDS
#pragma unroll
    for (int tt = 0; tt < 16; ++tt) {
      int row = 16 * tt + lr;
      int ov = (row * 64 + lg * 16) ^ (((row >> 1) & 3) << 4);
      bf16x8 va = *reinterpret_cast<const bf16x8*>(vbuf + ov);
      acc[tt] = __builtin_amdgcn_mfma_f32_16x16x32_bf16(va, pbu.v, acc[tt], 0, 0, 0);
    }
    __syncthreads();  // drain next-tile staging; protect buffer reuse
  }
  float inv = 1.f / lrun;
#pragma unroll
  for (int tt = 0; tt < 16; ++tt) {
    union { unsigned short u[4]; uint2 v; } pk;
#pragma unroll
    for (int r = 0; r < 4; ++r) pk.u[r] = f2bf(acc[tt][r] * inv);
    *reinterpret_cast<uint2*>(hrow + 16 * tt + 4 * lg) = pk.v;
  }
}

// ---------------- output projection + bias + residual, fp32 out ----------------
__global__ void __launch_bounds__(256) proj_res_kernel(
    const unsigned short* __restrict__ Wo, const unsigned short* __restrict__ HO,
    const float* __restrict__ bo, const float* __restrict__ x, float* __restrict__ out) {
  int b = blockIdx.z;
  int lane = threadIdx.x & 63, wid = threadIdx.x >> 6;
  int lr = lane & 15, lg = lane >> 4;
  int row0 = blockIdx.x * 128 + (wid >> 1) * 64;  // o
  int col0 = blockIdx.y * 128 + (wid & 1) * 64;   // n
  const unsigned short* hb = HO + (size_t)b * Nn * Cc;
  f32x4 acc[4][4] = {};
  for (int k0 = 0; k0 < 256; k0 += 32) {
    bf16x8 a[4], bb[4];
#pragma unroll
    for (int i = 0; i < 4; ++i) a[i] = ldb8(Wo + (size_t)(row0 + 16 * i + lr) * Cc + k0 + 8 * lg);
#pragma unroll
    for (int j = 0; j < 4; ++j) bb[j] = ldb8(hb + (size_t)(col0 + 16 * j + lr) * Cc + k0 + 8 * lg);
#pragma unroll
    for (int i = 0; i < 4; ++i)
#pragma unroll
      for (int j = 0; j < 4; ++j)
        acc[i][j] = __builtin_amdgcn_mfma_f32_16x16x32_bf16(a[i], bb[j], acc[i][j], 0, 0, 0);
  }
  const float* xb = x + (size_t)b * Cc * Nn;
  float* ob = out + (size_t)b * Cc * Nn;
#pragma unroll
  for (int i = 0; i < 4; ++i)
#pragma unroll
    for (int j = 0; j < 4; ++j)
#pragma unroll
      for (int r = 0; r < 4; ++r) {
        int o = row0 + 16 * i + 4 * lg + r;
        int n = col0 + 16 * j + lr;
        size_t idx = (size_t)o * Nn + n;
        ob[idx] = xb[idx] + bo[o] + acc[i][j][r];
      }
}

extern "C" void kernel_launch(void* const* d_in, const int* in_sizes, int n_in,
                              void* d_out, int out_size, void* d_ws, size_t ws_size,
                              hipStream_t stream) {
  const float* x  = (const float*)d_in[0];
  const float* gw = (const float*)d_in[1];
  const float* gb = (const float*)d_in[2];
  const float* wq = (const float*)d_in[3];
  const float* bq = (const float*)d_in[4];
  const float* wk = (const float*)d_in[5];
  const float* bk = (const float*)d_in[6];
  const float* wv = (const float*)d_in[7];
  const float* bv = (const float*)d_in[8];
  const float* wo = (const float*)d_in[9];
  const float* bo = (const float*)d_in[10];
  float* out = (float*)d_out;
  char* ws = (char*)d_ws;

  // workspace layout — NEVER exceed ws_size:
  //   [0, 512KB)   wbf: 4 weight matrices bf16
  //   [1MB, 17MB)  hT [B,N,C] bf16 (becomes attention output in-place)
  //   [17MB, ...)  K^T/V^T staging for BG batches (BG*1MB), BG adapted to ws_size
  unsigned short* wbf = (unsigned short*)ws;
  unsigned short* hT  = (unsigned short*)(ws + (1 << 20));
  const size_t KV_OFF = (size_t)17 << 20;
  const size_t perBatchKV = (size_t)Nn * Cc * 2 * 2;  // 1MB (KT + VT)
  size_t avail = ws_size > KV_OFF ? ws_size - KV_OFF : 0;
  int BG = 32;
  while (BG > 1 && (size_t)BG * perBatchKV > avail) BG >>= 1;

  cvt_w_kernel<<<dim3(256), dim3(256), 0, stream>>>(wq, wk, wv, wo, wbf);
  gn_fused_kernel<<<dim3(Bb * 32), dim3(256), 0, stream>>>(x, gw, gb, hT);

  unsigned short* KTg = (unsigned short*)(ws + KV_OFF);
  unsigned short* VTg = KTg + (size_t)BG * Nn * Cc;

  for (int g = 0; g < Bb; g += BG) {
    unsigned short* hTg = hT + (size_t)g * Nn * Cc;
    // KT[n][o] = sum_c hT[n][c] wk[o][c] + bk[o]   (stored [N,C] per batch)
    gemm_bt_kernel<<<dim3(8, 2, BG), dim3(256), 0, stream>>>(
        hTg, (size_t)Nn * Cc, wbf + 65536, 0, KTg, (size_t)Nn * Cc, bk, 0, Cc, Cc, Cc);
    // VT[o][n] = sum_c wv[o][c] hT[n][c] + bv[o]   (stored [C,N] per batch)
    gemm_bt_kernel<<<dim3(2, 8, BG), dim3(256), 0, stream>>>(
        wbf + 131072, 0, hTg, (size_t)Nn * Cc, VTg, (size_t)Cc * Nn, bv, 1, Cc, Cc, Nn);
    // fused Q-proj + attention, output in-place over hTg rows
    attn_kernel<<<dim3(Nn / 64, BG), dim3(256), 0, stream>>>(wbf, bq, hTg, KTg, VTg);
  }

  proj_res_kernel<<<dim3(2, 8, Bb), dim3(256), 0, stream>>>(wbf + 196608, hT, bo, x, out);
}

// Round 4
// 196.368 us; speedup vs baseline: 2.0465x; 1.1696x over previous
//
#include <hip/hip_runtime.h>

typedef __attribute__((ext_vector_type(8))) short bf16x8;
typedef __attribute__((ext_vector_type(4))) float f32x4;

constexpr int Bb = 32, Cc = 256, Nn = 1024;
constexpr float EPSf = 1e-5f;
constexpr float SCALE = 0.0625f; // 256^-0.5

__device__ __forceinline__ unsigned short f2bf(float f) {
  union { float f; unsigned u; } v; v.f = f;
  unsigned r = v.u + 0x7fffu + ((v.u >> 16) & 1u);
  return (unsigned short)(r >> 16);
}

__device__ __forceinline__ bf16x8 ldb8(const unsigned short* p) {
  return *reinterpret_cast<const bf16x8*>(p);
}

__device__ __forceinline__ void gload16(const void* g, void* l) {
  __builtin_amdgcn_global_load_lds((const __attribute__((address_space(1))) void*)g,
                                   (__attribute__((address_space(3))) void*)l, 16, 0, 0);
}

// ---------------- weight fp32 -> bf16 ----------------
__global__ void cvt_w_kernel(const float* __restrict__ wq, const float* __restrict__ wk,
                             const float* __restrict__ wv, const float* __restrict__ wo,
                             unsigned short* __restrict__ o) {
  int i = blockIdx.x * 256 + threadIdx.x;  // grid 256 x 256 = 65536
  o[i]          = f2bf(wq[i]);
  o[65536 + i]  = f2bf(wk[i]);
  o[131072 + i] = f2bf(wv[i]);
  o[196608 + i] = f2bf(wo[i]);
}

// ---------------- fused groupnorm: stats + apply in one pass ----------------
__global__ void __launch_bounds__(256) gn_fused_kernel(
    const float* __restrict__ x, const float* __restrict__ gw, const float* __restrict__ gb,
    unsigned short* __restrict__ hT) {
  int b = blockIdx.x >> 5, g = blockIdx.x & 31;
  const float4* xg = (const float4*)(x + ((size_t)b * 32 + g) * 8192);
  __shared__ float xs[8192];
  __shared__ float red[8];
  float s = 0.f, ss = 0.f;
  for (int i = threadIdx.x; i < 2048; i += 256) {
    float4 v = xg[i];
    ((float4*)xs)[i] = v;
    s += v.x + v.y + v.z + v.w;
    ss += v.x * v.x + v.y * v.y + v.z * v.z + v.w * v.w;
  }
  for (int o = 1; o < 64; o <<= 1) { s += __shfl_xor(s, o, 64); ss += __shfl_xor(ss, o, 64); }
  int wid = threadIdx.x >> 6;
  if ((threadIdx.x & 63) == 0) { red[wid] = s; red[4 + wid] = ss; }
  __syncthreads();
  float S  = red[0] + red[1] + red[2] + red[3];
  float SS = red[4] + red[5] + red[6] + red[7];
  float mean = S * (1.f / 8192.f);
  float rstd = rsqrtf(SS * (1.f / 8192.f) - mean * mean + EPSf);
  float w8[8], b8[8];
#pragma unroll
  for (int c = 0; c < 8; ++c) {
    w8[c] = gw[g * 8 + c] * rstd;
    b8[c] = gb[g * 8 + c] - mean * w8[c];
  }
  unsigned short* ob = hT + (size_t)b * Nn * Cc + g * 8;
#pragma unroll
  for (int k = 0; k < 4; ++k) {
    int n = threadIdx.x + 256 * k;
    union { unsigned short u[8]; uint4 v; } pk;
#pragma unroll
    for (int c = 0; c < 8; ++c) pk.u[c] = f2bf(xs[c * 1024 + n] * w8[c] + b8[c]);
    *reinterpret_cast<uint4*>(ob + (size_t)n * Cc) = pk.v;
  }
}

// ---------------- generic bf16 GEMM: D[row,col] = sum_k A[row,k]*Bt[col,k] + bias ----------------
__global__ void __launch_bounds__(256) gemm_bt_kernel(
    const unsigned short* __restrict__ A, size_t sA,
    const unsigned short* __restrict__ Bt, size_t sB,
    unsigned short* __restrict__ O, size_t sO,
    const float* __restrict__ bias, int biasRow,
    int lda, int ldb, int ldo) {
  int bz = blockIdx.z;
  A += (size_t)bz * sA; Bt += (size_t)bz * sB; O += (size_t)bz * sO;
  int lane = threadIdx.x & 63, wid = threadIdx.x >> 6;
  int lr = lane & 15, lg = lane >> 4;
  int row0 = blockIdx.x * 128 + (wid >> 1) * 64;
  int col0 = blockIdx.y * 128 + (wid & 1) * 64;
  f32x4 acc[4][4] = {};
  for (int k0 = 0; k0 < 256; k0 += 32) {
    bf16x8 a[4], bb[4];
#pragma unroll
    for (int i = 0; i < 4; ++i) a[i] = ldb8(A + (size_t)(row0 + 16 * i + lr) * lda + k0 + 8 * lg);
#pragma unroll
    for (int j = 0; j < 4; ++j) bb[j] = ldb8(Bt + (size_t)(col0 + 16 * j + lr) * ldb + k0 + 8 * lg);
#pragma unroll
    for (int i = 0; i < 4; ++i)
#pragma unroll
      for (int j = 0; j < 4; ++j)
        acc[i][j] = __builtin_amdgcn_mfma_f32_16x16x32_bf16(a[i], bb[j], acc[i][j], 0, 0, 0);
  }
#pragma unroll
  for (int i = 0; i < 4; ++i)
#pragma unroll
    for (int j = 0; j < 4; ++j)
#pragma unroll
      for (int r = 0; r < 4; ++r) {
        int row = row0 + 16 * i + 4 * lg + r;
        int col = col0 + 16 * j + lr;
        float v = acc[i][j][r] + (biasRow ? bias[row] : bias[col]);
        O[(size_t)row * ldo + col] = f2bf(v);
      }
}

// ---------------- fused Q-proj + flash attention, 8 waves, shared K/V staging ----------------
// hT: [BG,N,C] bf16 (groupnormed h; rows overwritten in-place with attention output)
// grid: (BG, 8) — batch-major so XCD = batch%8 (all q-tiles of a batch share an XCD's L2)
__global__ void __launch_bounds__(512, 2) attn_kernel(
    const unsigned short* __restrict__ wqb, const float* __restrict__ bq,
    unsigned short* __restrict__ hT,
    const unsigned short* __restrict__ KT, const unsigned short* __restrict__ VT) {
  int b = blockIdx.x;
  int tid = threadIdx.x;
  int lane = tid & 63, wid = tid >> 6;
  int lr = lane & 15, lg = lane >> 4;
  int n0 = blockIdx.y * 128 + wid * 16;
  unsigned short* hrow = hT + ((size_t)b * Nn + n0 + lr) * Cc;  // wave's 16 rows (by lr)
  const char* KTb = (const char*)(KT + (size_t)b * Nn * Cc);
  const char* VTb = (const char*)(VT + (size_t)b * Cc * Nn);

  // LDS: buf{0,1} of 32KB: K tile [32][512B] at +0, V tile [256][64B] at +16K
  __shared__ alignas(16) char lds[65536];

  // stage one 32-row KV tile (32KB) cooperatively across all 512 threads.
  // global_load_lds writes linearly; conflict-reducing XOR swizzle is applied by
  // inverse-swizzling the *global source* byte address (involution).
  auto stage = [&](int t, int buf) {
    char* kdst = lds + buf * 32768;
    char* vdst = kdst + 16384;
    const char* kg = KTb + (size_t)t * 32 * 512;  // 32 rows of K^T [N,C]
    const char* vg = VTb + (size_t)t * 64;        // 32 cols (2B each) of V^T [C,N]
#pragma unroll
    for (int r = 0; r < 2; ++r) {
      int Lb = r * 8192 + wid * 1024;
      int L = Lb + lane * 16;
      int lk = L ^ (((L >> 9) & 7) << 4);                 // K: 512B rows, swz bits 4-6
      gload16(kg + lk, kdst + Lb);
      int off = (L ^ (((L >> 7) & 3) << 4)) & 63;         // V: 64B rows, swz bits 4-5
      gload16(vg + (size_t)(L >> 6) * 2048 + off, vdst + Lb);
    }
  };

  stage(0, 0);  // overlap tile-0 staging with the Q projection (no LDS use below)

  // ---- Q on the fly, entirely in registers:
  // aq[t][r] = Q_raw[n0+lr][16t+4lg+r]; rearrange to B-fragment layout
  // (q[kk] word wi = bf16 pair for ch = 32kk+8lg+2wi) via cvt_pk + shuffles.
  bf16x8 q[8];
  {
    bf16x8 hfrag[8];
#pragma unroll
    for (int kk = 0; kk < 8; ++kk) hfrag[kk] = ldb8(hrow + 32 * kk + 8 * lg);
    unsigned wqp[16][2];
#pragma unroll
    for (int t = 0; t < 16; ++t) {
      f32x4 aq = {0.f, 0.f, 0.f, 0.f};
#pragma unroll
      for (int kk = 0; kk < 8; ++kk) {
        bf16x8 wf = ldb8(wqb + (size_t)(16 * t + lr) * Cc + 32 * kk + 8 * lg);
        aq = __builtin_amdgcn_mfma_f32_16x16x32_bf16(wf, hfrag[kk], aq, 0, 0, 0);
      }
      float4 bqv = *reinterpret_cast<const float4*>(bq + 16 * t + 4 * lg);
      float q0 = (aq[0] + bqv.x) * SCALE, q1 = (aq[1] + bqv.y) * SCALE;
      float q2 = (aq[2] + bqv.z) * SCALE, q3 = (aq[3] + bqv.w) * SCALE;
      asm("v_cvt_pk_bf16_f32 %0, %1, %2" : "=v"(wqp[t][0]) : "v"(q0), "v"(q1));
      asm("v_cvt_pk_bf16_f32 %0, %1, %2" : "=v"(wqp[t][1]) : "v"(q2), "v"(q3));
    }
    int srcA = lr + 16 * ((2 * lg) & 3);
    int srcB = lr + 16 * ((2 * lg + 1) & 3);
    int hi = lg >> 1;
#pragma unroll
    for (int kk = 0; kk < 8; ++kk) {
      unsigned a0 = __shfl(wqp[2 * kk][0], srcA, 64), b0 = __shfl(wqp[2 * kk + 1][0], srcA, 64);
      unsigned a1 = __shfl(wqp[2 * kk][1], srcA, 64), b1 = __shfl(wqp[2 * kk + 1][1], srcA, 64);
      unsigned a2 = __shfl(wqp[2 * kk][0], srcB, 64), b2 = __shfl(wqp[2 * kk + 1][0], srcB, 64);
      unsigned a3 = __shfl(wqp[2 * kk][1], srcB, 64), b3 = __shfl(wqp[2 * kk + 1][1], srcB, 64);
      union { unsigned w[4]; bf16x8 v; } u;
      u.w[0] = hi ? b0 : a0; u.w[1] = hi ? b1 : a1;
      u.w[2] = hi ? b2 : a2; u.w[3] = hi ? b3 : a3;
      q[kk] = u.v;
    }
  }
  __syncthreads();  // tile0 staged (vmcnt drained before barrier)

  f32x4 acc[16] = {};
  float mrun = -1e30f, lrun = 0.f;
  for (int t = 0; t < 32; ++t) {
    int cur = t & 1;
    if (t < 31) stage(t + 1, cur ^ 1);
    const char* kbuf = lds + cur * 32768;
    const char* vbuf = kbuf + 16384;
    // ---- QK^T from LDS (swizzled reads)
    f32x4 st0 = {0.f, 0.f, 0.f, 0.f}, st1 = {0.f, 0.f, 0.f, 0.f};
    __builtin_amdgcn_s_setprio(1);
#pragma unroll
    for (int kk = 0; kk < 8; ++kk) {
      int c = kk * 64 + lg * 16;
      int sx = (lr & 7) << 4;
      bf16x8 k0 = *reinterpret_cast<const bf16x8*>(kbuf + ((lr * 512 + c) ^ sx));
      bf16x8 k1 = *reinterpret_cast<const bf16x8*>(kbuf + (((lr + 16) * 512 + c) ^ sx));
      st0 = __builtin_amdgcn_mfma_f32_16x16x32_bf16(k0, q[kk], st0, 0, 0, 0);
      st1 = __builtin_amdgcn_mfma_f32_16x16x32_bf16(k1, q[kk], st1, 0, 0, 0);
    }
    __builtin_amdgcn_s_setprio(0);
    // lane holds S^T[m = 4lg+r (+16)][n = n0+lr] (scale folded into Q)
    float s0[4], s1[4], tm = -1e30f;
#pragma unroll
    for (int r = 0; r < 4; ++r) {
      s0[r] = st0[r]; s1[r] = st1[r];
      tm = fmaxf(tm, fmaxf(s0[r], s1[r]));
    }
    tm = fmaxf(tm, __shfl_xor(tm, 16, 64));
    tm = fmaxf(tm, __shfl_xor(tm, 32, 64));
    if (!__all(tm - mrun <= 8.f)) {  // defer-max (T13)
      float mnew = fmaxf(mrun, tm);
      float alpha = __expf(mrun - mnew);
#pragma unroll
      for (int u = 0; u < 16; ++u) {
        acc[u][0] *= alpha; acc[u][1] *= alpha; acc[u][2] *= alpha; acc[u][3] *= alpha;
      }
      lrun *= alpha;
      mrun = mnew;
    }
    float p0[4], p1[4], ps = 0.f;
#pragma unroll
    for (int r = 0; r < 4; ++r) {
      p0[r] = __expf(s0[r] - mrun); p1[r] = __expf(s1[r] - mrun);
      ps += p0[r] + p1[r];
    }
    ps += __shfl_xor(ps, 16, 64);
    ps += __shfl_xor(ps, 32, 64);
    lrun += ps;
    // ---- P -> bf16 packed + redistribute (4 cvt_pk + 8 shuffles)
    unsigned w00, w01, w10, w11;
    asm("v_cvt_pk_bf16_f32 %0, %1, %2" : "=v"(w00) : "v"(p0[0]), "v"(p0[1]));
    asm("v_cvt_pk_bf16_f32 %0, %1, %2" : "=v"(w01) : "v"(p0[2]), "v"(p0[3]));
    asm("v_cvt_pk_bf16_f32 %0, %1, %2" : "=v"(w10) : "v"(p1[0]), "v"(p1[1]));
    asm("v_cvt_pk_bf16_f32 %0, %1, %2" : "=v"(w11) : "v"(p1[2]), "v"(p1[3]));
    int sl0 = lr + 16 * (2 * (lg & 1));
    int sl1 = sl0 + 16;
    int hi = lg >> 1;
    union { unsigned w[4]; bf16x8 v; } pbu;
    {
      unsigned a = __shfl(w00, sl0, 64), c = __shfl(w10, sl0, 64);
      pbu.w[0] = hi ? c : a;
      unsigned a1 = __shfl(w01, sl0, 64), c1 = __shfl(w11, sl0, 64);
      pbu.w[1] = hi ? c1 : a1;
      unsigned a2 = __shfl(w00, sl1, 64), c2 = __shfl(w10, sl1, 64);
      pbu.w[2] = hi ? c2 : a2;
      unsigned a3 = __shfl(w01, sl1, 64), c3 = __shfl(w11, sl1, 64);
      pbu.w[3] = hi ? c3 : a3;
    }
    // ---- PV from LDS
    __builtin_amdgcn_s_setprio(1);
#pragma unroll
    for (int tt = 0; tt < 16; ++tt) {
      int row = 16 * tt + lr;
      int ov = (row * 64 + lg * 16) ^ (((row >> 1) & 3) << 4);
      bf16x8 va = *reinterpret_cast<const bf16x8*>(vbuf + ov);
      acc[tt] = __builtin_amdgcn_mfma_f32_16x16x32_bf16(va, pbu.v, acc[tt], 0, 0, 0);
    }
    __builtin_amdgcn_s_setprio(0);
    __syncthreads();  // drain next-tile staging; protect buffer reuse
  }
  float inv = 1.f / lrun;
#pragma unroll
  for (int tt = 0; tt < 16; ++tt) {
    union { unsigned short u[4]; uint2 v; } pk;
#pragma unroll
    for (int r = 0; r < 4; ++r) pk.u[r] = f2bf(acc[tt][r] * inv);
    *reinterpret_cast<uint2*>(hrow + 16 * tt + 4 * lg) = pk.v;
  }
}

// ---------------- output projection + bias + residual, fp32 out ----------------
__global__ void __launch_bounds__(256) proj_res_kernel(
    const unsigned short* __restrict__ Wo, const unsigned short* __restrict__ HO,
    const float* __restrict__ bo, const float* __restrict__ x, float* __restrict__ out) {
  int b = blockIdx.z;
  int lane = threadIdx.x & 63, wid = threadIdx.x >> 6;
  int lr = lane & 15, lg = lane >> 4;
  int row0 = blockIdx.x * 128 + (wid >> 1) * 64;  // o
  int col0 = blockIdx.y * 128 + (wid & 1) * 64;   // n
  const unsigned short* hb = HO + (size_t)b * Nn * Cc;
  f32x4 acc[4][4] = {};
  for (int k0 = 0; k0 < 256; k0 += 32) {
    bf16x8 a[4], bb[4];
#pragma unroll
    for (int i = 0; i < 4; ++i) a[i] = ldb8(Wo + (size_t)(row0 + 16 * i + lr) * Cc + k0 + 8 * lg);
#pragma unroll
    for (int j = 0; j < 4; ++j) bb[j] = ldb8(hb + (size_t)(col0 + 16 * j + lr) * Cc + k0 + 8 * lg);
#pragma unroll
    for (int i = 0; i < 4; ++i)
#pragma unroll
      for (int j = 0; j < 4; ++j)
        acc[i][j] = __builtin_amdgcn_mfma_f32_16x16x32_bf16(a[i], bb[j], acc[i][j], 0, 0, 0);
  }
  const float* xb = x + (size_t)b * Cc * Nn;
  float* ob = out + (size_t)b * Cc * Nn;
#pragma unroll
  for (int i = 0; i < 4; ++i)
#pragma unroll
    for (int j = 0; j < 4; ++j)
#pragma unroll
      for (int r = 0; r < 4; ++r) {
        int o = row0 + 16 * i + 4 * lg + r;
        int n = col0 + 16 * j + lr;
        size_t idx = (size_t)o * Nn + n;
        ob[idx] = xb[idx] + bo[o] + acc[i][j][r];
      }
}

extern "C" void kernel_launch(void* const* d_in, const int* in_sizes, int n_in,
                              void* d_out, int out_size, void* d_ws, size_t ws_size,
                              hipStream_t stream) {
  const float* x  = (const float*)d_in[0];
  const float* gw = (const float*)d_in[1];
  const float* gb = (const float*)d_in[2];
  const float* wq = (const float*)d_in[3];
  const float* bq = (const float*)d_in[4];
  const float* wk = (const float*)d_in[5];
  const float* bk = (const float*)d_in[6];
  const float* wv = (const float*)d_in[7];
  const float* bv = (const float*)d_in[8];
  const float* wo = (const float*)d_in[9];
  const float* bo = (const float*)d_in[10];
  float* out = (float*)d_out;
  char* ws = (char*)d_ws;

  // workspace layout — NEVER exceed ws_size:
  //   [0, 512KB)   wbf: 4 weight matrices bf16
  //   [1MB, 17MB)  hT [B,N,C] bf16 (becomes attention output in-place)
  //   [17MB, ...)  K^T/V^T staging for BG batches (BG*1MB), BG adapted to ws_size
  unsigned short* wbf = (unsigned short*)ws;
  unsigned short* hT  = (unsigned short*)(ws + (1 << 20));
  const size_t KV_OFF = (size_t)17 << 20;
  const size_t perBatchKV = (size_t)Nn * Cc * 2 * 2;  // 1MB (KT + VT)
  size_t avail = ws_size > KV_OFF ? ws_size - KV_OFF : 0;
  int BG = 32;
  while (BG > 1 && (size_t)BG * perBatchKV > avail) BG >>= 1;

  cvt_w_kernel<<<dim3(256), dim3(256), 0, stream>>>(wq, wk, wv, wo, wbf);
  gn_fused_kernel<<<dim3(Bb * 32), dim3(256), 0, stream>>>(x, gw, gb, hT);

  unsigned short* KTg = (unsigned short*)(ws + KV_OFF);
  unsigned short* VTg = KTg + (size_t)BG * Nn * Cc;

  for (int g = 0; g < Bb; g += BG) {
    unsigned short* hTg = hT + (size_t)g * Nn * Cc;
    // KT[n][o] = sum_c hT[n][c] wk[o][c] + bk[o]   (stored [N,C] per batch)
    gemm_bt_kernel<<<dim3(8, 2, BG), dim3(256), 0, stream>>>(
        hTg, (size_t)Nn * Cc, wbf + 65536, 0, KTg, (size_t)Nn * Cc, bk, 0, Cc, Cc, Cc);
    // VT[o][n] = sum_c wv[o][c] hT[n][c] + bv[o]   (stored [C,N] per batch)
    gemm_bt_kernel<<<dim3(2, 8, BG), dim3(256), 0, stream>>>(
        wbf + 131072, 0, hTg, (size_t)Nn * Cc, VTg, (size_t)Cc * Nn, bv, 1, Cc, Cc, Nn);
    // fused Q-proj + attention, 8 waves/block, batch-major grid (XCD locality)
    attn_kernel<<<dim3(BG, 8), dim3(512), 0, stream>>>(wbf, bq, hTg, KTg, VTg);
  }

  proj_res_kernel<<<dim3(2, 8, Bb), dim3(256), 0, stream>>>(wbf + 196608, hT, bo, x, out);
}